// Round 1
// baseline (1555.690 us; speedup 1.0000x reference)
//
#include <hip/hip_runtime.h>
#include <float.h>
#include <math.h>

#define BB 64
#define DD 512
#define SS 2048
#define KT 8

// ---------------- k1: transpose [B,D,S] -> [B,S,D] + per-(b,d) sums ----------------
__global__ __launch_bounds__(256)
void k_transpose_mean(const float* __restrict__ x, float* __restrict__ feature,
                      float* __restrict__ meansum) {
    __shared__ float tile[32][33];
    const int b  = blockIdx.z;
    const int d0 = blockIdx.y * 32;
    const int s0 = blockIdx.x * 32;
    const int tx = threadIdx.x;      // 0..31 (s on load, d on store)
    const int ty = threadIdx.y;      // 0..7
    const float* xb = x + (size_t)b * DD * SS;
    float v[4];
#pragma unroll
    for (int i = 0; i < 4; ++i) {
        const int d = d0 + ty + 8 * i;
        v[i] = xb[(size_t)d * SS + s0 + tx];
        tile[ty + 8 * i][tx] = v[i];
    }
    // mean partial: sum over the 32 s-values (tx) for each d row
#pragma unroll
    for (int i = 0; i < 4; ++i) {
        float s = v[i];
#pragma unroll
        for (int off = 16; off > 0; off >>= 1) s += __shfl_down(s, off, 32);
        if (tx == 0) atomicAdd(&meansum[b * DD + d0 + ty + 8 * i], s);
    }
    __syncthreads();
    float* fb = feature + (size_t)b * SS * DD;
#pragma unroll
    for (int i = 0; i < 4; ++i) {
        const int s = s0 + ty + 8 * i;
        fb[(size_t)s * DD + d0 + tx] = tile[tx][ty + 8 * i];
    }
}

// ---------------- k2: positional encoding PE[s, 2i]=sin, [2i+1]=cos ----------------
__global__ __launch_bounds__(256)
void k_pe(float* __restrict__ pe) {
    const int idx = blockIdx.x * 256 + threadIdx.x;   // S*512 threads
    const int s = idx >> 9;
    const int i = idx & 511;
    // compute in double, round once to f32 (closest to exact math & both f32/f64 refs)
    const double c = -9.210340371976184 / 1024.0;     // -ln(10000)/d_model
    const double dv = exp((double)(2 * i) * c);
    const double ang = (double)s * dv;
    pe[(size_t)s * 1024 + 2 * i]     = (float)sin(ang);
    pe[(size_t)s * 1024 + 2 * i + 1] = (float)cos(ang);
}

// ---------------- k3: PEW1[s,d] = sum_e PE[s,e]*W1[d,e] + b1[d] ----------------
__global__ __launch_bounds__(256)
void k_pew1(const float* __restrict__ pe, const float* __restrict__ W1,
            const float* __restrict__ b1, float* __restrict__ pew1) {
    __shared__ float As[16][68];
    __shared__ float Bs[16][68];
    const int tx = threadIdx.x, ty = threadIdx.y;     // 16x16
    const int tid = ty * 16 + tx;
    const int m0 = blockIdx.y * 64;                   // s
    const int n0 = blockIdx.x * 64;                   // d
    float acc[4][4] = {};
    for (int k0 = 0; k0 < 1024; k0 += 16) {
#pragma unroll
        for (int i = 0; i < 4; ++i) {
            const int e = tid + 256 * i;              // 0..1023
            const int r = e >> 4, c = e & 15;
            As[c][r] = pe[(size_t)(m0 + r) * 1024 + k0 + c];
            Bs[c][r] = W1[(size_t)(n0 + r) * 1024 + k0 + c];
        }
        __syncthreads();
#pragma unroll
        for (int kk = 0; kk < 16; ++kk) {
            float a[4], bv[4];
#pragma unroll
            for (int i = 0; i < 4; ++i) a[i] = As[kk][ty * 4 + i];
#pragma unroll
            for (int j = 0; j < 4; ++j) bv[j] = Bs[kk][tx * 4 + j];
#pragma unroll
            for (int i = 0; i < 4; ++i)
#pragma unroll
                for (int j = 0; j < 4; ++j)
                    acc[i][j] += a[i] * bv[j];
        }
        __syncthreads();
    }
#pragma unroll
    for (int i = 0; i < 4; ++i) {
        const int s = m0 + ty * 4 + i;
#pragma unroll
        for (int j = 0; j < 4; ++j) {
            const int d = n0 + tx * 4 + j;
            pew1[(size_t)s * 512 + d] = acc[i][j] + b1[d];
        }
    }
}

// ---------------- k4: g[b,d] = sum_e (meansum[b,e]/S) * W1[d, 512+e] ----------------
__global__ __launch_bounds__(512)
void k_g(const float* __restrict__ meansum, const float* __restrict__ W1,
         float* __restrict__ g) {
    const int b = blockIdx.x;
    const int d = threadIdx.x;                        // 512
    __shared__ float mrow[512];
    mrow[d] = meansum[b * 512 + d] * (1.0f / 2048.0f);
    __syncthreads();
    float acc = 0.f;
    const float* w = W1 + (size_t)d * 1024 + 512;
#pragma unroll 8
    for (int e = 0; e < 512; ++e) acc += mrow[e] * w[e];
    g[b * 512 + d] = acc;
}

// ---------------- k5: main fused GEMM -> score ----------------
// score[b,s] += sum_{d in tile} W2[d]*relu( sum_e feature[b,s,e]*W1[d,e] + PEW1[s,d] + g[b,d] )
__global__ __launch_bounds__(256)
void k_score(const float* __restrict__ feature, const float* __restrict__ W1,
             const float* __restrict__ pew1, const float* __restrict__ g,
             const float* __restrict__ W2, float* __restrict__ score) {
    __shared__ float As[16][68];
    __shared__ float Bs[16][68];
    const int tx = threadIdx.x, ty = threadIdx.y;     // 16x16
    const int tid = ty * 16 + tx;
    const int b  = blockIdx.z;
    const int m0 = blockIdx.y * 64;                   // s
    const int n0 = blockIdx.x * 64;                   // d
    const float* A = feature + (size_t)b * SS * DD;
    float acc[4][4] = {};
    for (int k0 = 0; k0 < 512; k0 += 16) {
#pragma unroll
        for (int i = 0; i < 4; ++i) {
            const int e = tid + 256 * i;
            const int r = e >> 4, c = e & 15;
            As[c][r] = A[(size_t)(m0 + r) * 512 + k0 + c];
            Bs[c][r] = W1[(size_t)(n0 + r) * 1024 + k0 + c];
        }
        __syncthreads();
#pragma unroll
        for (int kk = 0; kk < 16; ++kk) {
            float a[4], bv[4];
#pragma unroll
            for (int i = 0; i < 4; ++i) a[i] = As[kk][ty * 4 + i];
#pragma unroll
            for (int j = 0; j < 4; ++j) bv[j] = Bs[kk][tx * 4 + j];
#pragma unroll
            for (int i = 0; i < 4; ++i)
#pragma unroll
                for (int j = 0; j < 4; ++j)
                    acc[i][j] += a[i] * bv[j];
        }
        __syncthreads();
    }
    float w2v[4];
#pragma unroll
    for (int j = 0; j < 4; ++j) w2v[j] = W2[n0 + tx * 4 + j];
#pragma unroll
    for (int i = 0; i < 4; ++i) {
        const int s = m0 + ty * 4 + i;
        float sr = 0.f;
#pragma unroll
        for (int j = 0; j < 4; ++j) {
            const int d = n0 + tx * 4 + j;
            float h = acc[i][j] + pew1[(size_t)s * 512 + d] + g[b * 512 + d];
            h = fmaxf(h, 0.f);
            sr += w2v[j] * h;
        }
#pragma unroll
        for (int off = 8; off > 0; off >>= 1) sr += __shfl_down(sr, off, 16);
        if (tx == 0) atomicAdd(&score[b * SS + s], sr);
    }
}

// ---------------- k6: per-batch top-8 (jax tie-break), one-hot, gather ----------------
__global__ __launch_bounds__(256)
void k_topk(const float* __restrict__ score, const float* __restrict__ feature,
            float* __restrict__ indices, float* __restrict__ selected) {
    const int b = blockIdx.x;
    const int tid = threadIdx.x;
    __shared__ float sv[2048];
    __shared__ float rv[256];
    __shared__ int   ri[256];
    __shared__ int   chosen[8];
    for (int i = tid; i < 2048; i += 256) sv[i] = score[b * 2048 + i];
    __syncthreads();
    for (int k = 0; k < 8; ++k) {
        float bestv = -FLT_MAX; int besti = 0x7fffffff;
        for (int i = tid; i < 2048; i += 256) {
            const float v = sv[i];
            if (v > bestv || (v == bestv && i < besti)) { bestv = v; besti = i; }
        }
        rv[tid] = bestv; ri[tid] = besti;
        __syncthreads();
        for (int off = 128; off > 0; off >>= 1) {
            if (tid < off) {
                const float v2 = rv[tid + off]; const int i2 = ri[tid + off];
                if (v2 > rv[tid] || (v2 == rv[tid] && i2 < ri[tid])) { rv[tid] = v2; ri[tid] = i2; }
            }
            __syncthreads();
        }
        if (tid == 0) { chosen[k] = ri[0]; sv[ri[0]] = -FLT_MAX; }
        __syncthreads();
    }
    if (tid == 0) {
        for (int i = 1; i < 8; ++i) {          // ascending insertion sort
            const int v = chosen[i]; int j = i - 1;
            while (j >= 0 && chosen[j] > v) { chosen[j + 1] = chosen[j]; --j; }
            chosen[j + 1] = v;
        }
    }
    __syncthreads();
    if (tid < 8)
        indices[((size_t)b * 8 + tid) * 2048 + chosen[tid]] = 1.0f;
    for (int i = tid; i < 8 * 512; i += 256) {
        const int k = i >> 9, d = i & 511;
        selected[((size_t)b * 8 + k) * 512 + d] =
            feature[((size_t)b * 2048 + chosen[k]) * 512 + d];
    }
}

extern "C" void kernel_launch(void* const* d_in, const int* in_sizes, int n_in,
                              void* d_out, int out_size, void* d_ws, size_t ws_size,
                              hipStream_t stream) {
    const float* x  = (const float*)d_in[0];   // [B, D, S]
    const float* W1 = (const float*)d_in[1];   // [D, 2D]
    const float* b1 = (const float*)d_in[2];   // [D]
    const float* W2 = (const float*)d_in[3];   // [1, D]
    // b2 (d_in[4]) is a uniform shift -> does not affect top-k; outputs don't use it.

    float* out      = (float*)d_out;
    float* indices  = out;                                    // B*K*S
    float* selected = out + (size_t)BB * KT * SS;             // B*K*D
    float* feature  = selected + (size_t)BB * KT * DD;        // B*S*D

    char*  ws      = (char*)d_ws;
    float* meansum = (float*)ws;                              // B*D   (128 KB)
    float* score   = (float*)(ws + (131072));                 // B*S   (512 KB)
    float* pe      = (float*)(ws + (131072 + 524288));        // S*1024 (8 MB)
    float* pew1    = (float*)(ws + (131072 + 524288 + 8388608));        // S*D (4 MB)
    float* g       = (float*)(ws + (131072 + 524288 + 8388608 + 4194304)); // B*D

    // zero atomic targets + one-hot output region
    hipMemsetAsync(d_ws, 0, 131072 + 524288, stream);
    hipMemsetAsync(d_out, 0, (size_t)BB * KT * SS * sizeof(float), stream);

    k_transpose_mean<<<dim3(SS / 32, DD / 32, BB), dim3(32, 8), 0, stream>>>(x, feature, meansum);
    k_pe<<<dim3(SS * 512 / 256), dim3(256), 0, stream>>>(pe);
    k_pew1<<<dim3(512 / 64, 2048 / 64), dim3(16, 16), 0, stream>>>(pe, W1, b1, pew1);
    k_g<<<dim3(BB), dim3(512), 0, stream>>>(meansum, W1, g);
    k_score<<<dim3(512 / 64, 2048 / 64, BB), dim3(16, 16), 0, stream>>>(feature, W1, pew1, g, W2, score);
    k_topk<<<dim3(BB), dim3(256), 0, stream>>>(score, feature, indices, selected);
}